// Round 11
// baseline (157.474 us; speedup 1.0000x reference)
//
#include <hip/hip_runtime.h>
#include <math.h>

#define LN 8      // layers
#define NRBF 256
#define FD 16
#define OUTD 3
#define KC (-0.72134752044f)   // -0.5 * log2(e)

typedef __attribute__((ext_vector_type(8))) short short8;    // 8 x bf16
typedef __attribute__((ext_vector_type(4))) float floatx4;
typedef __attribute__((ext_vector_type(2))) float floatx2;

__device__ __forceinline__ short f2bf(float f) {
    unsigned u = __builtin_bit_cast(unsigned, f);
    u += 0x7fffu + ((u >> 16) & 1u);          // RNE
    return (short)(u >> 16);
}

// 16x16x32 layouts, nt-MAJOR (one n-tile's full j-chain contiguous):
//   PKB: short8 entry g = nt*512 + j*64 + lane   (8 KB per nt, 128 KB total)
//        lane l: n = nt*16+(l&15), kq = l>>4; elem e: k = kq*8+e,
//        feature f = kq*4+(e>>1); e even -> KC*A_f ; e odd -> -2*KC*A_f*C_f
//   EPI: float4 entry nt*128 + j*16 + (n&15) = {W'0, W'1, W'2, 0}  (2 KB per nt)
//        W'o = W[o][j*256+n] * exp2(KC * t3prefix_j[n])

__global__ __launch_bounds__(256) void prep(
    const float* __restrict__ centers, const float* __restrict__ betas,
    const float* __restrict__ W, short* __restrict__ PKB, float* __restrict__ EPI)
{
    __shared__ float ls[LN * 32];
    int blk = blockIdx.x;
    int tid = threadIdx.x;
    if (blk < 32) {
        int g    = blk * 256 + tid;        // = nt*512 + j*64 + lane (linear)
        int lane = g & 63;
        int j    = (g >> 6) & 7;
        int nt   = g >> 9;
        int n    = nt * 16 + (lane & 15);
        int kq   = lane >> 4;
        size_t base = ((size_t)(j * NRBF + n)) * FD + kq * 4;
        float4 bq = *(const float4*)(betas + base);
        float4 cq = *(const float4*)(centers + base);
        float a0 = KC * __expf(bq.x), a1 = KC * __expf(bq.y);
        float a2 = KC * __expf(bq.z), a3 = KC * __expf(bq.w);
        short8 v;
        v[0] = f2bf(a0); v[1] = f2bf(-2.0f * a0 * cq.x);
        v[2] = f2bf(a1); v[3] = f2bf(-2.0f * a1 * cq.y);
        v[4] = f2bf(a2); v[5] = f2bf(-2.0f * a2 * cq.z);
        v[6] = f2bf(a3); v[7] = f2bf(-2.0f * a3 * cq.w);
        *((short8*)(PKB + (size_t)g * 8)) = v;
    } else {
        int jj = tid >> 5;                  // 0..7
        int nl = tid & 31;
        int n  = (blk - 32) * 32 + nl;
        const float* bp = betas   + ((size_t)(jj * NRBF + n)) * FD;
        const float* cp = centers + ((size_t)(jj * NRBF + n)) * FD;
        float s = 0.f;
#pragma unroll
        for (int q = 0; q < 4; ++q) {
            float4 bq = *(const float4*)(bp + q * 4);
            float4 cq = *(const float4*)(cp + q * 4);
            s = fmaf(__expf(bq.x) * cq.x, cq.x, s);
            s = fmaf(__expf(bq.y) * cq.y, cq.y, s);
            s = fmaf(__expf(bq.z) * cq.z, cq.z, s);
            s = fmaf(__expf(bq.w) * cq.w, cq.w, s);
        }
        ls[jj * 32 + nl] = s;
        __syncthreads();
        float t3 = 0.f;
        for (int j2 = 0; j2 <= jj; ++j2) t3 += ls[j2 * 32 + nl];
        float E = __builtin_amdgcn_exp2f(KC * t3);
        float4 e;
        e.x = W[0 * (LN * NRBF) + jj * NRBF + n] * E;
        e.y = W[1 * (LN * NRBF) + jj * NRBF + n] * E;
        e.z = W[2 * (LN * NRBF) + jj * NRBF + n] * E;
        e.w = 0.f;
        ((float4*)EPI)[((size_t)(n >> 4) * 128) + jj * 16 + (n & 15)] = e;
    }
}

// build an A-fragment: elem e even -> x_f^2, odd -> x_f  (f = kq*4 + e>>1)
// NOTE: macro parameter must NOT be named x/y/z/w (member-access capture!)
#define CVT(dst, vv)  do {                                         \
        short8 f_;                                                 \
        f_[0] = f2bf((vv).x * (vv).x); f_[1] = f2bf((vv).x);       \
        f_[2] = f2bf((vv).y * (vv).y); f_[3] = f2bf((vv).y);       \
        f_[4] = f2bf((vv).z * (vv).z); f_[5] = f2bf((vv).z);       \
        f_[6] = f2bf((vv).w * (vv).w); f_[7] = f2bf((vv).w);       \
        (dst) = f_; } while (0)

// One wave owns a 32-SAMPLE tile (two 16x16 A-halves) x all 256 n x 8 layers.
// The two halves SHARE each B-fragment read and each ep read: per (nt,j),
// 1 pk ds_read + 1 ep ds_read serve 2 MFMAs + 8 exps (vs 4 in R8).
// Rationale (R10 post-mortem): duration == VALU-busy(34us, exp-dominated;
// v_exp_f32 ~17cyc/wave-instr) + LDS-pipe(31us) with near-zero overlap, in
// every variant; occupancy/chains/barrier-removal all null. R10 shared the
// A-frag across B-tiles (LDS/sample unchanged -> null); sharing B across
// A-halves halves the LDS term: 31 -> ~16us. One-j-lag pipeline kept.
//
// REGISTER DISCIPLINE (rounds 2-10 post-mortems):
//  - nt-loop MUST be unroll 1 (scheduler hoist -> spill churn, R3/R4).
//  - j-loop MUST be fully unrolled (runtime j -> dyn-indexed reg arrays, R5).
//  - launch_bounds must NOT request min-waves (arch/acc split spill, R2/R3).
//  - spill sentinel: FETCH ~26MB / WRITE ~1.2MB. GB-scale => scratch churn.
//  - L2-direct operand reads regress (R9): MFMA operands want LDS latency.
__global__ __launch_bounds__(256) void rbf_mfma(
    const float* __restrict__ feats, const short* __restrict__ PKB,
    const float* __restrict__ EPI, const float* __restrict__ bias,
    float* __restrict__ out, int B)
{
    __shared__ short8 pk_s[2][8 * 64];    // 2 x 8 KB
    __shared__ float4 ep_s[2][8 * 16];    // 2 x 2 KB

    int tid  = threadIdx.x;
    int lane = tid & 63;
    int w    = tid >> 6;
    int ntile = (B + 31) >> 5;            // 32-sample tiles
    int tile = blockIdx.x * 4 + w;
    bool tvalid = (tile < ntile);
    if (!tvalid) tile = ntile - 1;        // duplicate work, no store
    int b0 = tile * 32;
    int m  = lane & 15;                   // sample-in-half (A-row), D-col = n16
    int kq = lane >> 4;
    int brow0 = b0 + m;      if (brow0 >= B) brow0 = B - 1;
    int brow1 = b0 + 16 + m; if (brow1 >= B) brow1 = B - 1;
    const float* xrow0 = feats + (size_t)brow0 * (LN * FD) + kq * 4;
    const float* xrow1 = feats + (size_t)brow1 * (LN * FD) + kq * 4;

#define STAGE(buf, ntv)                                                         \
    do {                                                                        \
        _Pragma("unroll")                                                       \
        for (int q = 0; q < 2; ++q) {                                           \
            const short* gp = PKB + ((size_t)(ntv) * 512 + w * 128 + q * 64 + lane) * 8; \
            __builtin_amdgcn_global_load_lds(                                   \
                (const __attribute__((address_space(1))) void*)gp,              \
                (__attribute__((address_space(3))) void*)&pk_s[buf][w * 128 + q * 64], \
                16, 0, 0);                                                      \
        }                                                                       \
        if (lane < 32) {                                                        \
            const float* ge = EPI + ((size_t)(ntv) * 128 + w * 32 + lane) * 4;  \
            __builtin_amdgcn_global_load_lds(                                   \
                (const __attribute__((address_space(1))) void*)ge,              \
                (__attribute__((address_space(3))) void*)&ep_s[buf][w * 32],    \
                16, 0, 0);                                                      \
        }                                                                       \
    } while (0)

// exps + projection for one layer, one half (4 rows); o2 packed pairwise
#define EXPPROJ(accv, ev, oo, zz)                                  \
    do {                                                           \
        floatx2 exy_ = { (ev).x, (ev).y };                         \
        floatx2 ezz_ = { (ev).z, (ev).z };                         \
        float rv0_ = __builtin_amdgcn_exp2f((accv)[0]);            \
        float rv1_ = __builtin_amdgcn_exp2f((accv)[1]);            \
        float rv2_ = __builtin_amdgcn_exp2f((accv)[2]);            \
        float rv3_ = __builtin_amdgcn_exp2f((accv)[3]);            \
        oo[0] += (floatx2){rv0_, rv0_} * exy_;                     \
        oo[1] += (floatx2){rv1_, rv1_} * exy_;                     \
        oo[2] += (floatx2){rv2_, rv2_} * exy_;                     \
        oo[3] += (floatx2){rv3_, rv3_} * exy_;                     \
        zz[0] += (floatx2){rv0_, rv1_} * ezz_;                     \
        zz[1] += (floatx2){rv2_, rv3_} * ezz_;                     \
    } while (0)

    STAGE(0, 0);   // issue first LDS fill; hides under the af-build below

    // A-fragments for 8 layers x 2 halves (64 VGPRs), STATIC index only
    short8 af0[LN], af1[LN];
#pragma unroll
    for (int j = 0; j < LN; ++j) {
        float4 xa = *(const float4*)(xrow0 + j * FD);
        float4 xb = *(const float4*)(xrow1 + j * FD);
        CVT(af0[j], xa);
        CVT(af1[j], xb);
    }

    floatx2 o01A[4], o01B[4];  // per-row {sum*W'0, sum*W'1}
    floatx2 ozA[2],  ozB[2];   // rows packed pairwise for W'2
#pragma unroll
    for (int r = 0; r < 4; ++r) { o01A[r] = (floatx2){0.f, 0.f}; o01B[r] = (floatx2){0.f, 0.f}; }
    ozA[0] = (floatx2){0.f, 0.f}; ozA[1] = (floatx2){0.f, 0.f};
    ozB[0] = (floatx2){0.f, 0.f}; ozB[1] = (floatx2){0.f, 0.f};

    __syncthreads();

#pragma unroll 1
    for (int nt = 0; nt < 16; ++nt) {
        int cur = nt & 1;
        if (nt < 15) STAGE(cur ^ 1, nt + 1);

        floatx4 accA = (floatx4){0.f, 0.f, 0.f, 0.f};
        floatx4 accB = (floatx4){0.f, 0.f, 0.f, 0.f};
        floatx4 accpA, accpB;   // one-j-lag snapshots (written before read)

#pragma unroll
        for (int j = 0; j < LN; ++j) {
            short8 bf = pk_s[cur][j * 64 + lane];          // ONE read, 2 MFMAs
            accA = __builtin_amdgcn_mfma_f32_16x16x32_bf16(af0[j], bf, accA, 0, 0, 0);
            accB = __builtin_amdgcn_mfma_f32_16x16x32_bf16(af1[j], bf, accB, 0, 0, 0);
            if (j > 0) {                  // finish layer j-1, both halves, ONE e
                float4 e = ep_s[cur][(j - 1) * 16 + m];
                EXPPROJ(accpA, e, o01A, ozA);
                EXPPROJ(accpB, e, o01B, ozB);
            }
            accpA = accA;                 // snapshots after MFMA j
            accpB = accB;
        }
        {   // tail: layer 7, both halves
            float4 e = ep_s[cur][7 * 16 + m];
            EXPPROJ(accpA, e, o01A, ozA);
            EXPPROJ(accpB, e, o01B, ozB);
        }
        __syncthreads();
    }
#undef STAGE
#undef EXPPROJ

    // reduce over the 16 n-lanes (xor 1,2,4,8 stays within kq group)
    float oacc[24];
#pragma unroll
    for (int r = 0; r < 4; ++r) {
        oacc[r * 3 + 0]  = o01A[r].x;
        oacc[r * 3 + 1]  = o01A[r].y;
        oacc[r * 3 + 2]  = (r & 1) ? ozA[r >> 1].y : ozA[r >> 1].x;
        oacc[12 + r * 3 + 0] = o01B[r].x;
        oacc[12 + r * 3 + 1] = o01B[r].y;
        oacc[12 + r * 3 + 2] = (r & 1) ? ozB[r >> 1].y : ozB[r >> 1].x;
    }
#pragma unroll
    for (int i = 0; i < 24; ++i) {
        oacc[i] += __shfl_xor(oacc[i], 1);
        oacc[i] += __shfl_xor(oacc[i], 2);
        oacc[i] += __shfl_xor(oacc[i], 4);
        oacc[i] += __shfl_xor(oacc[i], 8);
    }

    if (tvalid && m < OUTD) {
        float bv = bias[m];
#pragma unroll
        for (int r = 0; r < 4; ++r) {
            int row0 = b0 + kq * 4 + r;          // half 0: D-row = kq*4+reg
            int row1 = b0 + 16 + kq * 4 + r;     // half 1
            if (row0 < B) out[(size_t)row0 * OUTD + m] = oacc[r * 3 + m] + bv;
            if (row1 < B) out[(size_t)row1 * OUTD + m] = oacc[12 + r * 3 + m] + bv;
        }
    }
}

extern "C" void kernel_launch(void* const* d_in, const int* in_sizes, int n_in,
                              void* d_out, int out_size, void* d_ws, size_t ws_size,
                              hipStream_t stream) {
    // inputs: 0=x (UNUSED by reference), 1=feats, 2=centers, 3=betas, 4=W, 5=b
    const float* feats   = (const float*)d_in[1];
    const float* centers = (const float*)d_in[2];
    const float* betas   = (const float*)d_in[3];
    const float* W       = (const float*)d_in[4];
    const float* bias    = (const float*)d_in[5];
    float* out = (float*)d_out;
    int B = in_sizes[1] / (LN * FD);

    short* PKB = (short*)d_ws;                       // 65536 shorts = 128 KB
    float* EPI = (float*)((char*)d_ws + 65536 * 2);  // 8192 floats = 32 KB

    prep<<<40, 256, 0, stream>>>(centers, betas, W, PKB, EPI);

    int tiles  = (B + 31) / 32;                      // 32-sample tiles
    int blocks = (tiles + 3) / 4;
    rbf_mfma<<<blocks, 256, 0, stream>>>(feats, PKB, EPI, bias, out, B);
}

// Round 12
// 147.436 us; speedup vs baseline: 1.0681x; 1.0681x over previous
//
#include <hip/hip_runtime.h>
#include <math.h>

#define LN 8      // layers
#define NRBF 256
#define FD 16
#define OUTD 3
#define KC (-0.72134752044f)   // -0.5 * log2(e)

typedef __attribute__((ext_vector_type(8))) short short8;    // 8 x bf16
typedef __attribute__((ext_vector_type(4))) float floatx4;
typedef __attribute__((ext_vector_type(2))) float floatx2;

__device__ __forceinline__ short f2bf(float f) {
    unsigned u = __builtin_bit_cast(unsigned, f);
    u += 0x7fffu + ((u >> 16) & 1u);          // RNE
    return (short)(u >> 16);
}

// 16x16x32 layouts, nt-MAJOR (one n-tile's full j-chain contiguous):
//   PKB: short8 entry g = nt*512 + j*64 + lane   (8 KB per nt, 128 KB total)
//        lane l: n = nt*16+(l&15), kq = l>>4; elem e: k = kq*8+e,
//        feature f = kq*4+(e>>1); e even -> KC*A_f ; e odd -> -2*KC*A_f*C_f
//   EPI: float4 entry nt*128 + j*16 + (n&15) = {W'0, W'1, W'2, 0}  (2 KB per nt)
//        W'o = W[o][j*256+n] * exp2(KC * t3prefix_j[n])

__global__ __launch_bounds__(256) void prep(
    const float* __restrict__ centers, const float* __restrict__ betas,
    const float* __restrict__ W, short* __restrict__ PKB, float* __restrict__ EPI)
{
    __shared__ float ls[LN * 32];
    int blk = blockIdx.x;
    int tid = threadIdx.x;
    if (blk < 32) {
        int g    = blk * 256 + tid;        // = nt*512 + j*64 + lane (linear)
        int lane = g & 63;
        int j    = (g >> 6) & 7;
        int nt   = g >> 9;
        int n    = nt * 16 + (lane & 15);
        int kq   = lane >> 4;
        size_t base = ((size_t)(j * NRBF + n)) * FD + kq * 4;
        float4 bq = *(const float4*)(betas + base);
        float4 cq = *(const float4*)(centers + base);
        float a0 = KC * __expf(bq.x), a1 = KC * __expf(bq.y);
        float a2 = KC * __expf(bq.z), a3 = KC * __expf(bq.w);
        short8 v;
        v[0] = f2bf(a0); v[1] = f2bf(-2.0f * a0 * cq.x);
        v[2] = f2bf(a1); v[3] = f2bf(-2.0f * a1 * cq.y);
        v[4] = f2bf(a2); v[5] = f2bf(-2.0f * a2 * cq.z);
        v[6] = f2bf(a3); v[7] = f2bf(-2.0f * a3 * cq.w);
        *((short8*)(PKB + (size_t)g * 8)) = v;
    } else {
        int jj = tid >> 5;                  // 0..7
        int nl = tid & 31;
        int n  = (blk - 32) * 32 + nl;
        const float* bp = betas   + ((size_t)(jj * NRBF + n)) * FD;
        const float* cp = centers + ((size_t)(jj * NRBF + n)) * FD;
        float s = 0.f;
#pragma unroll
        for (int q = 0; q < 4; ++q) {
            float4 bq = *(const float4*)(bp + q * 4);
            float4 cq = *(const float4*)(cp + q * 4);
            s = fmaf(__expf(bq.x) * cq.x, cq.x, s);
            s = fmaf(__expf(bq.y) * cq.y, cq.y, s);
            s = fmaf(__expf(bq.z) * cq.z, cq.z, s);
            s = fmaf(__expf(bq.w) * cq.w, cq.w, s);
        }
        ls[jj * 32 + nl] = s;
        __syncthreads();
        float t3 = 0.f;
        for (int j2 = 0; j2 <= jj; ++j2) t3 += ls[j2 * 32 + nl];
        float E = __builtin_amdgcn_exp2f(KC * t3);
        float4 e;
        e.x = W[0 * (LN * NRBF) + jj * NRBF + n] * E;
        e.y = W[1 * (LN * NRBF) + jj * NRBF + n] * E;
        e.z = W[2 * (LN * NRBF) + jj * NRBF + n] * E;
        e.w = 0.f;
        ((float4*)EPI)[((size_t)(n >> 4) * 128) + jj * 16 + (n & 15)] = e;
    }
}

// build an A-fragment: elem e even -> x_f^2, odd -> x_f  (f = kq*4 + e>>1)
// NOTE: macro parameter must NOT be named x/y/z/w (member-access capture!)
#define CVT(dst, vv)  do {                                         \
        short8 f_;                                                 \
        f_[0] = f2bf((vv).x * (vv).x); f_[1] = f2bf((vv).x);       \
        f_[2] = f2bf((vv).y * (vv).y); f_[3] = f2bf((vv).y);       \
        f_[4] = f2bf((vv).z * (vv).z); f_[5] = f2bf((vv).z);       \
        f_[6] = f2bf((vv).w * (vv).w); f_[7] = f2bf((vv).w);       \
        (dst) = f_; } while (0)

// R12: 1-WAVE BLOCKS, NO LDS, NO BARRIERS, depth-4 register pipeline.
// One wave = one 32-sample tile (two 16x16 A-halves sharing every B-fragment
// and ep vector -> halved memory volume, R11) x all 256 n x 8 layers.
// pk/ep operands are loaded straight from L2 into 4 rotating named slots
// (bf0-3 / ep0-3), refilled 4 flat-steps (nt*8+j) ahead of use -> ~300-500cyc
// of latency cover per wave; the wave never stalls on operand delivery, so
// fill no longer depends on TLP (which 11 rounds proved is capped ~2.5-3
// waves/SIMD effective). Grid = 3125 one-wave blocks (fixes R11's 782-block
// granularity collapse). One-j-lag exp pipeline kept (accp snapshots).
//
// REGISTER DISCIPLINE (rounds 2-11 post-mortems):
//  - nt-loop MUST be unroll 1 (scheduler hoist -> spill churn, R3/R4).
//  - j-steps fully unrolled, ALL slot indices static (runtime idx -> R5).
//  - launch_bounds must NOT request min-waves (arch/acc split spill, R2/R3).
//  - spill sentinel: FETCH ~26MB / WRITE ~1.2MB. GB-scale => scratch churn.
__global__ __launch_bounds__(64) void rbf_mfma(
    const float* __restrict__ feats, const short* __restrict__ PKB,
    const float* __restrict__ EPI, const float* __restrict__ bias,
    float* __restrict__ out, int B)
{
    int lane = threadIdx.x & 63;
    int ntile = (B + 31) >> 5;            // 32-sample tiles
    int tile = blockIdx.x;
    bool tvalid = (tile < ntile);
    if (!tvalid) tile = ntile - 1;
    int b0 = tile * 32;
    int m  = lane & 15;                   // sample-in-half (A-row), D-col = n16
    int kq = lane >> 4;
    int brow0 = b0 + m;      if (brow0 >= B) brow0 = B - 1;
    int brow1 = b0 + 16 + m; if (brow1 >= B) brow1 = B - 1;
    const float* xrow0 = feats + (size_t)brow0 * (LN * FD) + kq * 4;
    const float* xrow1 = feats + (size_t)brow1 * (LN * FD) + kq * 4;

    const short8* pkb8 = (const short8*)PKB;
    const float4* epi4 = (const float4*)EPI;
    const short8* pb = pkb8 + lane;       // + nt*512 + j*64
    const float4* eb = epi4 + m;          // + nt*128 + j*16

// exps + projection for one layer, one half (4 rows); o2 packed pairwise
#define EXPPROJ(accv, ev, oo, zz)                                  \
    do {                                                           \
        floatx2 exy_ = { (ev).x, (ev).y };                         \
        floatx2 ezz_ = { (ev).z, (ev).z };                         \
        float rv0_ = __builtin_amdgcn_exp2f((accv)[0]);            \
        float rv1_ = __builtin_amdgcn_exp2f((accv)[1]);            \
        float rv2_ = __builtin_amdgcn_exp2f((accv)[2]);            \
        float rv3_ = __builtin_amdgcn_exp2f((accv)[3]);            \
        oo[0] += (floatx2){rv0_, rv0_} * exy_;                     \
        oo[1] += (floatx2){rv1_, rv1_} * exy_;                     \
        oo[2] += (floatx2){rv2_, rv2_} * exy_;                     \
        oo[3] += (floatx2){rv3_, rv3_} * exy_;                     \
        zz[0] += (floatx2){rv0_, rv1_} * ezz_;                     \
        zz[1] += (floatx2){rv2_, rv3_} * ezz_;                     \
    } while (0)

    // A-fragments for 8 layers x 2 halves (64 VGPRs), STATIC index only
    short8 af0[LN], af1[LN];
#pragma unroll
    for (int j = 0; j < LN; ++j) {
        float4 xa = *(const float4*)(xrow0 + j * FD);
        float4 xb = *(const float4*)(xrow1 + j * FD);
        CVT(af0[j], xa);
        CVT(af1[j], xb);
    }

    floatx2 o01A[4], o01B[4];
    floatx2 ozA[2],  ozB[2];
#pragma unroll
    for (int r = 0; r < 4; ++r) { o01A[r] = (floatx2){0.f, 0.f}; o01B[r] = (floatx2){0.f, 0.f}; }
    ozA[0] = (floatx2){0.f, 0.f}; ozA[1] = (floatx2){0.f, 0.f};
    ozB[0] = (floatx2){0.f, 0.f}; ozB[1] = (floatx2){0.f, 0.f};

    // depth-4 prefetch slots (flat step s = nt*8 + j; slot = s & 3)
    short8 bf0 = pb[0 * 64], bf1 = pb[1 * 64], bf2 = pb[2 * 64], bf3 = pb[3 * 64];
    float4 ep0 = eb[0 * 16], ep1 = eb[1 * 16], ep2 = eb[2 * 16], ep3 = eb[3 * 16];

    floatx4 accA, accB, accpA, accpB;

// one step: MFMA both halves on slot BF, refill BF with BNEXT,
// run exps of layer j-1 on snapshot using slot EP, refill EP with ENEXT.
#define MSTEP(J, BF, BNEXT, EP, ENEXT)                                       \
    do {                                                                     \
        accA = __builtin_amdgcn_mfma_f32_16x16x32_bf16(af0[J], BF, accA, 0, 0, 0); \
        accB = __builtin_amdgcn_mfma_f32_16x16x32_bf16(af1[J], BF, accB, 0, 0, 0); \
        BF = BNEXT;                                                          \
        { float4 e_ = EP; EP = ENEXT;                                        \
          EXPPROJ(accpA, e_, o01A, ozA);                                     \
          EXPPROJ(accpB, e_, o01B, ozB); }                                   \
        accpA = accA; accpB = accB;                                          \
    } while (0)

#pragma unroll 1
    for (int nt = 0; nt < 16; ++nt) {
        const short8* pc = pb + (size_t)nt * 512;
        const float4* ec = eb + (size_t)nt * 128;
        const short8* pn = (nt < 15) ? (pc + 512) : pc;   // clamp: no OOB
        const float4* en = (nt < 15) ? (ec + 128) : ec;

        accA = (floatx4){0.f, 0.f, 0.f, 0.f};
        accB = (floatx4){0.f, 0.f, 0.f, 0.f};

        // j=0: no exps yet (layer -1 doesn't exist)
        accA = __builtin_amdgcn_mfma_f32_16x16x32_bf16(af0[0], bf0, accA, 0, 0, 0);
        accB = __builtin_amdgcn_mfma_f32_16x16x32_bf16(af1[0], bf0, accB, 0, 0, 0);
        bf0 = pc[4 * 64];
        accpA = accA; accpB = accB;

        MSTEP(1, bf1, pc[5 * 64], ep0, ec[4 * 16]);   // uses e0, refills e4
        MSTEP(2, bf2, pc[6 * 64], ep1, ec[5 * 16]);   // e1 -> e5
        MSTEP(3, bf3, pc[7 * 64], ep2, ec[6 * 16]);   // e2 -> e6
        MSTEP(4, bf0, pn[0 * 64], ep3, ec[7 * 16]);   // e3 -> e7
        MSTEP(5, bf1, pn[1 * 64], ep0, en[0 * 16]);   // e4 -> next e0
        MSTEP(6, bf2, pn[2 * 64], ep1, en[1 * 16]);   // e5 -> next e1
        MSTEP(7, bf3, pn[3 * 64], ep2, en[2 * 16]);   // e6 -> next e2

        {   // tail: layer 7 exps; uses e7 (slot3), refill next e3
            float4 e_ = ep3; ep3 = en[3 * 16];
            EXPPROJ(accpA, e_, o01A, ozA);
            EXPPROJ(accpB, e_, o01B, ozB);
        }
    }
#undef MSTEP
#undef EXPPROJ

    // reduce over the 16 n-lanes (xor 1,2,4,8 stays within kq group)
    float oacc[24];
#pragma unroll
    for (int r = 0; r < 4; ++r) {
        oacc[r * 3 + 0]  = o01A[r].x;
        oacc[r * 3 + 1]  = o01A[r].y;
        oacc[r * 3 + 2]  = (r & 1) ? ozA[r >> 1].y : ozA[r >> 1].x;
        oacc[12 + r * 3 + 0] = o01B[r].x;
        oacc[12 + r * 3 + 1] = o01B[r].y;
        oacc[12 + r * 3 + 2] = (r & 1) ? ozB[r >> 1].y : ozB[r >> 1].x;
    }
#pragma unroll
    for (int i = 0; i < 24; ++i) {
        oacc[i] += __shfl_xor(oacc[i], 1);
        oacc[i] += __shfl_xor(oacc[i], 2);
        oacc[i] += __shfl_xor(oacc[i], 4);
        oacc[i] += __shfl_xor(oacc[i], 8);
    }

    if (tvalid && m < OUTD) {
        float bv = bias[m];
#pragma unroll
        for (int r = 0; r < 4; ++r) {
            int row0 = b0 + kq * 4 + r;          // half 0: D-row = kq*4+reg
            int row1 = b0 + 16 + kq * 4 + r;     // half 1
            if (row0 < B) out[(size_t)row0 * OUTD + m] = oacc[r * 3 + m] + bv;
            if (row1 < B) out[(size_t)row1 * OUTD + m] = oacc[12 + r * 3 + m] + bv;
        }
    }
}

extern "C" void kernel_launch(void* const* d_in, const int* in_sizes, int n_in,
                              void* d_out, int out_size, void* d_ws, size_t ws_size,
                              hipStream_t stream) {
    // inputs: 0=x (UNUSED by reference), 1=feats, 2=centers, 3=betas, 4=W, 5=b
    const float* feats   = (const float*)d_in[1];
    const float* centers = (const float*)d_in[2];
    const float* betas   = (const float*)d_in[3];
    const float* W       = (const float*)d_in[4];
    const float* bias    = (const float*)d_in[5];
    float* out = (float*)d_out;
    int B = in_sizes[1] / (LN * FD);

    short* PKB = (short*)d_ws;                       // 65536 shorts = 128 KB
    float* EPI = (float*)((char*)d_ws + 65536 * 2);  // 8192 floats = 32 KB

    prep<<<40, 256, 0, stream>>>(centers, betas, W, PKB, EPI);

    int tiles = (B + 31) / 32;                       // one 1-wave block per tile
    rbf_mfma<<<tiles, 64, 0, stream>>>(feats, PKB, EPI, bias, out, B);
}

// Round 13
// 140.411 us; speedup vs baseline: 1.1215x; 1.0500x over previous
//
#include <hip/hip_runtime.h>
#include <math.h>

#define LN 8      // layers
#define NRBF 256
#define FD 16
#define OUTD 3
#define KC (-0.72134752044f)   // -0.5 * log2(e)

typedef __attribute__((ext_vector_type(8))) short short8;    // 8 x bf16
typedef __attribute__((ext_vector_type(4))) float floatx4;
typedef __attribute__((ext_vector_type(2))) float floatx2;

__device__ __forceinline__ short f2bf(float f) {
    unsigned u = __builtin_bit_cast(unsigned, f);
    u += 0x7fffu + ((u >> 16) & 1u);          // RNE
    return (short)(u >> 16);
}

// 16x16x32 layouts, nt-MAJOR (one n-tile's full j-chain contiguous):
//   PKB: short8 entry g = nt*512 + j*64 + lane   (8 KB per nt, 128 KB total)
//        lane l: n = nt*16+(l&15), kq = l>>4; elem e: k = kq*8+e,
//        feature f = kq*4+(e>>1); e even -> KC*A_f ; e odd -> -2*KC*A_f*C_f
//   EPI: float4 entry nt*128 + j*16 + (n&15) = {W'0, W'1, W'2, 0}  (2 KB per nt)
//        W'o = W[o][j*256+n] * exp2(KC * t3prefix_j[n])

__global__ __launch_bounds__(256) void prep(
    const float* __restrict__ centers, const float* __restrict__ betas,
    const float* __restrict__ W, short* __restrict__ PKB, float* __restrict__ EPI)
{
    __shared__ float ls[LN * 32];
    int blk = blockIdx.x;
    int tid = threadIdx.x;
    if (blk < 32) {
        int g    = blk * 256 + tid;        // = nt*512 + j*64 + lane (linear)
        int lane = g & 63;
        int j    = (g >> 6) & 7;
        int nt   = g >> 9;
        int n    = nt * 16 + (lane & 15);
        int kq   = lane >> 4;
        size_t base = ((size_t)(j * NRBF + n)) * FD + kq * 4;
        float4 bq = *(const float4*)(betas + base);
        float4 cq = *(const float4*)(centers + base);
        float a0 = KC * __expf(bq.x), a1 = KC * __expf(bq.y);
        float a2 = KC * __expf(bq.z), a3 = KC * __expf(bq.w);
        short8 v;
        v[0] = f2bf(a0); v[1] = f2bf(-2.0f * a0 * cq.x);
        v[2] = f2bf(a1); v[3] = f2bf(-2.0f * a1 * cq.y);
        v[4] = f2bf(a2); v[5] = f2bf(-2.0f * a2 * cq.z);
        v[6] = f2bf(a3); v[7] = f2bf(-2.0f * a3 * cq.w);
        *((short8*)(PKB + (size_t)g * 8)) = v;
    } else {
        int jj = tid >> 5;                  // 0..7
        int nl = tid & 31;
        int n  = (blk - 32) * 32 + nl;
        const float* bp = betas   + ((size_t)(jj * NRBF + n)) * FD;
        const float* cp = centers + ((size_t)(jj * NRBF + n)) * FD;
        float s = 0.f;
#pragma unroll
        for (int q = 0; q < 4; ++q) {
            float4 bq = *(const float4*)(bp + q * 4);
            float4 cq = *(const float4*)(cp + q * 4);
            s = fmaf(__expf(bq.x) * cq.x, cq.x, s);
            s = fmaf(__expf(bq.y) * cq.y, cq.y, s);
            s = fmaf(__expf(bq.z) * cq.z, cq.z, s);
            s = fmaf(__expf(bq.w) * cq.w, cq.w, s);
        }
        ls[jj * 32 + nl] = s;
        __syncthreads();
        float t3 = 0.f;
        for (int j2 = 0; j2 <= jj; ++j2) t3 += ls[j2 * 32 + nl];
        float E = __builtin_amdgcn_exp2f(KC * t3);
        float4 e;
        e.x = W[0 * (LN * NRBF) + jj * NRBF + n] * E;
        e.y = W[1 * (LN * NRBF) + jj * NRBF + n] * E;
        e.z = W[2 * (LN * NRBF) + jj * NRBF + n] * E;
        e.w = 0.f;
        ((float4*)EPI)[((size_t)(n >> 4) * 128) + jj * 16 + (n & 15)] = e;
    }
}

// build an A-fragment: elem e even -> x_f^2, odd -> x_f  (f = kq*4 + e>>1)
// NOTE: macro parameter must NOT be named x/y/z/w (member-access capture!)
#define CVT(dst, vv)  do {                                         \
        short8 f_;                                                 \
        f_[0] = f2bf((vv).x * (vv).x); f_[1] = f2bf((vv).x);       \
        f_[2] = f2bf((vv).y * (vv).y); f_[3] = f2bf((vv).y);       \
        f_[4] = f2bf((vv).z * (vv).z); f_[5] = f2bf((vv).z);       \
        f_[6] = f2bf((vv).w * (vv).w); f_[7] = f2bf((vv).w);       \
        (dst) = f_; } while (0)

// FINAL (R13 = R8 reverted): one wave owns a 16-sample tile x all 256 n x
// 8 layers, nt-OUTER / j-INNER, one-j-lag exp pipeline, per-nt PKB/EPI
// slices double-buffered in LDS via global_load_lds(16B).
//
// ROOFLINE RATIONALE (rounds 0-12): the op is VALU/trans-THROUGHPUT-bound.
// Fixed work: 204.8M rbf values, each needing 1 v_exp_f32 (~16 exec-cyc/
// wave-instr on the trans unit) + ~3 fma -> ~30us of pipe-execution per
// SIMD at 2.4GHz. Wave64 VALU execs 2 cyc on the SIMD32, so the VALUBusy
// PMC (issue events) saturates near ~50%: the measured invariant
// {busy 31-34us, dur 62-67us, VALUBusy ~50%} across FIVE structures
// (LDS-staged / L2-direct / 2-chain / B-shared / barrier-free reg-pipeline,
// occupancy 1.7-2.9 w/SIMD) is the pipe-full signature, not a fill gap.
// exp count is algorithmically irreducible; projection can't be factored
// (W' varies per n) and MFMA-izing it costs as much in cvt_pk as it saves.
//
// REGISTER DISCIPLINE (rounds 2-7 post-mortems):
//  - nt-loop MUST be unroll 1 (scheduler hoist -> spill churn, R3/R4).
//  - j-loop MUST be fully unrolled (runtime j -> dyn-indexed reg arrays, R5).
//  - launch_bounds must NOT request min-waves (arch/acc split spill, R2/R3).
//  - spill sentinel: FETCH ~26MB / WRITE ~1.2MB. GB-scale => scratch churn.
__global__ __launch_bounds__(256) void rbf_mfma(
    const float* __restrict__ feats, const short* __restrict__ PKB,
    const float* __restrict__ EPI, const float* __restrict__ bias,
    float* __restrict__ out, int B)
{
    __shared__ short8 pk_s[2][8 * 64];    // 2 x 8 KB
    __shared__ float4 ep_s[2][8 * 16];    // 2 x 2 KB

    int tid  = threadIdx.x;
    int lane = tid & 63;
    int w    = tid >> 6;
    int ntile = (B + 15) >> 4;
    int tile = blockIdx.x * 4 + w;
    bool tvalid = (tile < ntile);
    if (!tvalid) tile = ntile - 1;        // duplicate work, no store
    int b0 = tile * 16;
    int m  = lane & 15;                   // sample-in-tile (A-row), D-col = n16
    int kq = lane >> 4;
    int brow = b0 + m; if (brow >= B) brow = B - 1;
    const float* xrow = feats + (size_t)brow * (LN * FD) + kq * 4;

#define STAGE(buf, ntv)                                                         \
    do {                                                                        \
        _Pragma("unroll")                                                       \
        for (int q = 0; q < 2; ++q) {                                           \
            const short* gp = PKB + ((size_t)(ntv) * 512 + w * 128 + q * 64 + lane) * 8; \
            __builtin_amdgcn_global_load_lds(                                   \
                (const __attribute__((address_space(1))) void*)gp,              \
                (__attribute__((address_space(3))) void*)&pk_s[buf][w * 128 + q * 64], \
                16, 0, 0);                                                      \
        }                                                                       \
        if (lane < 32) {                                                        \
            const float* ge = EPI + ((size_t)(ntv) * 128 + w * 32 + lane) * 4;  \
            __builtin_amdgcn_global_load_lds(                                   \
                (const __attribute__((address_space(1))) void*)ge,              \
                (__attribute__((address_space(3))) void*)&ep_s[buf][w * 32],    \
                16, 0, 0);                                                      \
        }                                                                       \
    } while (0)

// exps + projection for one layer (4 rows); o2 packed pairwise for pk_fma
#define EXPPROJ(accv, ev)                                          \
    do {                                                           \
        floatx2 exy_ = { (ev).x, (ev).y };                         \
        floatx2 ezz_ = { (ev).z, (ev).z };                         \
        float rv0_ = __builtin_amdgcn_exp2f((accv)[0]);            \
        float rv1_ = __builtin_amdgcn_exp2f((accv)[1]);            \
        float rv2_ = __builtin_amdgcn_exp2f((accv)[2]);            \
        float rv3_ = __builtin_amdgcn_exp2f((accv)[3]);            \
        o01[0] += (floatx2){rv0_, rv0_} * exy_;                    \
        o01[1] += (floatx2){rv1_, rv1_} * exy_;                    \
        o01[2] += (floatx2){rv2_, rv2_} * exy_;                    \
        o01[3] += (floatx2){rv3_, rv3_} * exy_;                    \
        oz[0]  += (floatx2){rv0_, rv1_} * ezz_;                    \
        oz[1]  += (floatx2){rv2_, rv3_} * ezz_;                    \
    } while (0)

    STAGE(0, 0);   // issue first LDS fill; hides under the af-build below

    // A-fragments for all 8 layers (32 VGPRs), built once, STATIC index only
    short8 af[LN];
#pragma unroll
    for (int j = 0; j < LN; ++j) {
        float4 xa = *(const float4*)(xrow + j * FD);
        CVT(af[j], xa);
    }

    floatx2 o01[4];   // per-row {sum*W'0, sum*W'1}
    floatx2 oz[2];    // rows packed pairwise for W'2
#pragma unroll
    for (int r = 0; r < 4; ++r) o01[r] = (floatx2){0.f, 0.f};
    oz[0] = (floatx2){0.f, 0.f}; oz[1] = (floatx2){0.f, 0.f};

    __syncthreads();

#pragma unroll 1
    for (int nt = 0; nt < 16; ++nt) {
        int cur = nt & 1;
        if (nt < 15) STAGE(cur ^ 1, nt + 1);

        floatx4 acc = (floatx4){0.f, 0.f, 0.f, 0.f};
        floatx4 accp;   // one-j-lag snapshot (written before first read)

#pragma unroll
        for (int j = 0; j < LN; ++j) {
            short8 bf = pk_s[cur][j * 64 + lane];
            acc = __builtin_amdgcn_mfma_f32_16x16x32_bf16(af[j], bf, acc, 0, 0, 0);
            if (j > 0) {                   // finish layer j-1 while MFMA j flies
                float4 e = ep_s[cur][(j - 1) * 16 + m];
                EXPPROJ(accp, e);
            }
            accp = acc;                    // snapshot after MFMA j completes
        }
        {   // tail: layer 7
            float4 e = ep_s[cur][7 * 16 + m];
            EXPPROJ(accp, e);
        }
        __syncthreads();
    }
#undef STAGE
#undef EXPPROJ

    // reduce over the 16 n-lanes (xor 1,2,4,8 stays within kq group)
    float oacc[12];
#pragma unroll
    for (int r = 0; r < 4; ++r) {
        oacc[r * 3 + 0] = o01[r].x;
        oacc[r * 3 + 1] = o01[r].y;
        oacc[r * 3 + 2] = (r & 1) ? oz[r >> 1].y : oz[r >> 1].x;
    }
#pragma unroll
    for (int i = 0; i < 12; ++i) {
        oacc[i] += __shfl_xor(oacc[i], 1);
        oacc[i] += __shfl_xor(oacc[i], 2);
        oacc[i] += __shfl_xor(oacc[i], 4);
        oacc[i] += __shfl_xor(oacc[i], 8);
    }

    if (tvalid && m < OUTD) {
        float bv = bias[m];
#pragma unroll
        for (int r = 0; r < 4; ++r) {
            int row = b0 + kq * 4 + r;     // D-row = (lane>>4)*4 + reg
            if (row < B) out[(size_t)row * OUTD + m] = oacc[r * 3 + m] + bv;
        }
    }
}

extern "C" void kernel_launch(void* const* d_in, const int* in_sizes, int n_in,
                              void* d_out, int out_size, void* d_ws, size_t ws_size,
                              hipStream_t stream) {
    // inputs: 0=x (UNUSED by reference), 1=feats, 2=centers, 3=betas, 4=W, 5=b
    const float* feats   = (const float*)d_in[1];
    const float* centers = (const float*)d_in[2];
    const float* betas   = (const float*)d_in[3];
    const float* W       = (const float*)d_in[4];
    const float* bias    = (const float*)d_in[5];
    float* out = (float*)d_out;
    int B = in_sizes[1] / (LN * FD);

    short* PKB = (short*)d_ws;                       // 65536 shorts = 128 KB
    float* EPI = (float*)((char*)d_ws + 65536 * 2);  // 8192 floats = 32 KB

    prep<<<40, 256, 0, stream>>>(centers, betas, W, PKB, EPI);

    int tiles  = (B + 15) / 16;
    int blocks = (tiles + 3) / 4;
    rbf_mfma<<<blocks, 256, 0, stream>>>(feats, PKB, EPI, bias, out, B);
}